// Round 8
// baseline (185.020 us; speedup 1.0000x reference)
//
#include <hip/hip_runtime.h>
#include <hip/hip_bf16.h>

#define NB 4
#define CIN 128
#define NN 4096
#define DD 16
#define GG 4
#define EPSGN 1e-5f
#define L2E 1.4426950408889634f

typedef __attribute__((ext_vector_type(8))) short short8_t;
typedef __attribute__((ext_vector_type(4))) float f32x4;
typedef __attribute__((ext_vector_type(16))) float f32x16;

// ---------------- workspace layout (float slots) ----------------
#define OFF_Q      0          // q f32 [b][n][16]       262144
#define OFF_T      262144     // t f32 [b][n][o]        262144
#define OFF_GN     524288     // f32 [b][g][2]          32 (pad to 524320)
#define OFF_QB     524320     // bf16 [b][n][32]: d0..15 = q, 16..17 = lri2 hi/lo, 18..19 = 1,1
#define OFF_KB     786464     // bf16 [b][m][32]: d0..15 = k*log2e, 16..17 = 1,1, 18..19 = lci2 hi/lo
#define OFF_VTB    1048608    // bf16 [b][d][4096]      131072 slots
// total 1179680 floats = 4.72 MB

static __device__ __forceinline__ int waveid() {
    return __builtin_amdgcn_readfirstlane((int)(threadIdx.x >> 6));
}
static __device__ __forceinline__ unsigned int bfpk(float a, float b) {
    union { __hip_bfloat162 h2; unsigned int u; } c;
    c.h2 = __float22bfloat162_rn(float2{a, b});
    return c.u;
}
static __device__ __forceinline__ unsigned short bf1(float a) {
    union { __hip_bfloat16 h1; unsigned short u; } c;
    c.h1 = __float2bfloat16(a);
    return c.u;
}

// K1: 1x1 convs + positional terms -> q (f32), qb/kb (bf16; k scaled by log2e),
// vtb (bf16 transposed [b][d][n]).  512 thr = 8 waves, 3-stage LDS tree.
__global__ __launch_bounds__(512) void k_qkv(
    const float* __restrict__ x_q, const float* __restrict__ x_kv,
    const float* __restrict__ xyz_q, const float* __restrict__ xyz_kv,
    const float* __restrict__ w_qk, const float* __restrict__ w_v,
    const float* __restrict__ b_v, const float* __restrict__ w_pos_q,
    const float* __restrict__ w_pos_kv,
    float* __restrict__ q, unsigned short* __restrict__ qb,
    unsigned short* __restrict__ kb, unsigned short* __restrict__ vtb,
    float* __restrict__ gnacc)
{
    __shared__ float part[4][64][49];
    int lane = threadIdx.x & 63;
    int w = waveid();                  // 0..7
    int g0 = blockIdx.x * 64;          // b*NN + n base
    int b = g0 >> 12;
    int n = (g0 & (NN - 1)) + lane;

    if (blockIdx.x == 0 && threadIdx.x < 32) gnacc[threadIdx.x] = 0.f;

    const float* xq = x_q  + (size_t)b * CIN * NN + n;
    const float* xk = x_kv + (size_t)b * CIN * NN + n;

    float aq[DD], ak[DD], av[DD];
#pragma unroll
    for (int d = 0; d < DD; ++d) { aq[d] = 0.f; ak[d] = 0.f; av[d] = 0.f; }

    for (int ci = 0; ci < 16; ++ci) {
        int c = w * 16 + ci;
        float vq = xq[(size_t)c * NN];
        float vk = xk[(size_t)c * NN];
#pragma unroll
        for (int d = 0; d < DD; ++d) {
            float wq = w_qk[d * CIN + c];            // uniform -> scalar
            aq[d] = fmaf(wq, vq, aq[d]);
            ak[d] = fmaf(wq, vk, ak[d]);
            av[d] = fmaf(w_v[d * CIN + c], vk, av[d]);
        }
    }

    if (w >= 4) {
#pragma unroll
        for (int d = 0; d < DD; ++d) {
            part[w - 4][lane][d]      = aq[d];
            part[w - 4][lane][d + 16] = ak[d];
            part[w - 4][lane][d + 32] = av[d];
        }
    }
    __syncthreads();
    if (w < 4) {
#pragma unroll
        for (int d = 0; d < DD; ++d) {
            aq[d] += part[w][lane][d];
            ak[d] += part[w][lane][d + 16];
            av[d] += part[w][lane][d + 32];
        }
    }
    __syncthreads();
    if (w == 2 || w == 3) {
#pragma unroll
        for (int d = 0; d < DD; ++d) {
            part[w - 2][lane][d]      = aq[d];
            part[w - 2][lane][d + 16] = ak[d];
            part[w - 2][lane][d + 32] = av[d];
        }
    }
    __syncthreads();
    if (w < 2) {
#pragma unroll
        for (int d = 0; d < DD; ++d) {
            aq[d] += part[w][lane][d];
            ak[d] += part[w][lane][d + 16];
            av[d] += part[w][lane][d + 32];
        }
    }
    __syncthreads();
    if (w == 1) {
#pragma unroll
        for (int d = 0; d < DD; ++d) {
            part[0][lane][d]      = aq[d];
            part[0][lane][d + 16] = ak[d];
            part[0][lane][d + 32] = av[d];
        }
    }
    __syncthreads();
    if (w == 0) {
#pragma unroll
        for (int d = 0; d < DD; ++d) {
            aq[d] += part[0][lane][d];
            ak[d] += part[0][lane][d + 16];
            av[d] += part[0][lane][d + 32];
        }
        float pq0 = xyz_q[((size_t)b * 3 + 0) * NN + n];
        float pq1 = xyz_q[((size_t)b * 3 + 1) * NN + n];
        float pq2 = xyz_q[((size_t)b * 3 + 2) * NN + n];
        float pk0 = xyz_kv[((size_t)b * 3 + 0) * NN + n];
        float pk1 = xyz_kv[((size_t)b * 3 + 1) * NN + n];
        float pk2 = xyz_kv[((size_t)b * 3 + 2) * NN + n];
        size_t row = (size_t)g0 + lane;
        float qv[DD], kv[DD];
#pragma unroll
        for (int d = 0; d < DD; ++d) {
            float posq = w_pos_q[d * 3] * pq0 + w_pos_q[d * 3 + 1] * pq1 + w_pos_q[d * 3 + 2] * pq2;
            float posk = w_pos_kv[d * 3] * pk0 + w_pos_kv[d * 3 + 1] * pk1 + w_pos_kv[d * 3 + 2] * pk2;
            qv[d] = aq[d] + posq;
            kv[d] = (ak[d] + posk) * L2E;            // exp2 domain
            q[row * DD + d] = qv[d];
            vtb[((size_t)(b * DD + d)) * NN + n] = bf1(av[d] + b_v[d] + posk);
        }
        unsigned int* qbw = (unsigned int*)(qb + row * 32);
        unsigned int* kbw = (unsigned int*)(kb + row * 32);
#pragma unroll
        for (int h = 0; h < 8; ++h) {
            qbw[h] = bfpk(qv[2 * h], qv[2 * h + 1]);
            kbw[h] = bfpk(kv[2 * h], kv[2 * h + 1]);
        }
        qbw[8] = 0u;                 // lri2 slot (k_rows writes)
        qbw[9] = bfpk(1.f, 1.f);     // picks up lci2 from kb[18..19]
        kbw[8] = bfpk(1.f, 1.f);     // picks up lri2 from qb[16..17]
        kbw[9] = 0u;                 // lci2 slot (k_cols writes)
#pragma unroll
        for (int h = 10; h < 16; ++h) { qbw[h] = 0u; kbw[h] = 0u; }
    }
}

// K2: rowsum via swapped 32x32x16 MFMA (K=16, pads unread): D[m][n], n=lane&31.
// s = log2e*e; rowsum = sum 2^s; writes lri2 = -log2(rowsum) into qb[n][16..17].
// grid (NN/32, NB), block 512; dual accumulation chains.
__global__ __launch_bounds__(512) void k_rows(
    unsigned short* __restrict__ qb, const unsigned short* __restrict__ kb)
{
    __shared__ float red[8][32];
    int lane = threadIdx.x & 63;
    int w = waveid();
    int l31 = lane & 31, h = lane >> 5;
    int b = blockIdx.y;
    int n0 = blockIdx.x * 32;

    unsigned short* qbb = qb + (size_t)b * NN * 32;
    const unsigned short* kbb = kb + (size_t)b * NN * 32;
    short8_t qf = *reinterpret_cast<const short8_t*>(qbb + (n0 + l31) * 32 + 8 * h);

    const f32x16 z16 = {0.f,0.f,0.f,0.f,0.f,0.f,0.f,0.f,0.f,0.f,0.f,0.f,0.f,0.f,0.f,0.f};
    float rs0 = 0.f, rs1 = 0.f;
    for (int mt = w; mt < 128; mt += 16) {
        short8_t kf0 = *reinterpret_cast<const short8_t*>(kbb + ((mt) * 32 + l31) * 32 + 8 * h);
        short8_t kf1 = *reinterpret_cast<const short8_t*>(kbb + ((mt + 8) * 32 + l31) * 32 + 8 * h);
        f32x16 c0 = __builtin_amdgcn_mfma_f32_32x32x16_bf16(kf0, qf, z16, 0, 0, 0);
        f32x16 c1 = __builtin_amdgcn_mfma_f32_32x32x16_bf16(kf1, qf, z16, 0, 0, 0);
#pragma unroll
        for (int r = 0; r < 16; ++r) rs0 += exp2f(c0[r]);
#pragma unroll
        for (int r = 0; r < 16; ++r) rs1 += exp2f(c1[r]);
    }
    float rs = rs0 + rs1;
    rs += __shfl_xor(rs, 32);
    if (lane < 32) red[w][l31] = rs;
    __syncthreads();
    if (threadIdx.x < 32) {
        float s = 0.f;
#pragma unroll
        for (int ww = 0; ww < 8; ++ww) s += red[ww][threadIdx.x];
        float lri = -log2f(s);
        float hi = __bfloat162float(__float2bfloat16(lri));
        *(unsigned int*)(qbb + (n0 + threadIdx.x) * 32 + 16) = bfpk(lri, lri - hi);
    }
}

// K3: colsum via non-swapped 16x16x32 MFMA, K=32 incl. pads (e' = s + lri2).
// cs = sum_n 2^e'; writes lci2 = -log2(1e-9+cs) into kb[m][18..19].
// grid (NN/16, NB), block 256; dual chains.
__global__ __launch_bounds__(256) void k_cols(
    const unsigned short* __restrict__ qb, unsigned short* __restrict__ kb)
{
    __shared__ float red[4][16];
    int lane = threadIdx.x & 63;
    int w = waveid();
    int j = lane & 15, g = lane >> 4;
    int b = blockIdx.y;
    int m0 = blockIdx.x * 16;

    unsigned short* kbb = kb + (size_t)b * NN * 32;
    const unsigned short* qbb = qb + (size_t)b * NN * 32;
    short8_t kf = *reinterpret_cast<const short8_t*>(kbb + (m0 + j) * 32 + 8 * g);

    float cs0 = 0.f, cs1 = 0.f;
    for (int nt = w; nt < 256; nt += 8) {
        short8_t qf0 = *reinterpret_cast<const short8_t*>(qbb + ((nt) * 16 + j) * 32 + 8 * g);
        short8_t qf1 = *reinterpret_cast<const short8_t*>(qbb + ((nt + 4) * 16 + j) * 32 + 8 * g);
        f32x4 c0 = __builtin_amdgcn_mfma_f32_16x16x32_bf16(qf0, kf, (f32x4){0.f, 0.f, 0.f, 0.f}, 0, 0, 0);
        f32x4 c1 = __builtin_amdgcn_mfma_f32_16x16x32_bf16(qf1, kf, (f32x4){0.f, 0.f, 0.f, 0.f}, 0, 0, 0);
        cs0 += exp2f(c0[0]) + exp2f(c0[1]) + exp2f(c0[2]) + exp2f(c0[3]);
        cs1 += exp2f(c1[0]) + exp2f(c1[1]) + exp2f(c1[2]) + exp2f(c1[3]);
    }
    float cs = cs0 + cs1;
    cs += __shfl_xor(cs, 16);
    cs += __shfl_xor(cs, 32);
    if (lane < 16) red[w][lane] = cs;
    __syncthreads();
    if (threadIdx.x < 16) {
        float s = red[0][threadIdx.x] + red[1][threadIdx.x] + red[2][threadIdx.x] + red[3][threadIdx.x];
        float lci = -log2f(1e-9f + s);
        float hi = __bfloat162float(__float2bfloat16(lci));
        *(unsigned int*)(kbb + (m0 + threadIdx.x) * 32 + 18) = bfpk(lci, lci - hi);
    }
}

// K4 body: one 32-m chunk. e' = s + lri2 + lci2 via pads; P = 2^e' ->
// bf16 repack (per-buffer LDS, b64 writes) -> PV mfma accumulate.
static __device__ __forceinline__ void xr_body(
    int M, unsigned int* __restrict__ plds,
    const unsigned short* __restrict__ kbb, const unsigned short* __restrict__ vtbb,
    short8_t qf, int j, int g, f32x4& acc)
{
    short8_t kf0 = *reinterpret_cast<const short8_t*>(kbb + (M + j) * 32 + 8 * g);
    short8_t kf1 = *reinterpret_cast<const short8_t*>(kbb + (M + 16 + j) * 32 + 8 * g);
    f32x4 c0 = __builtin_amdgcn_mfma_f32_16x16x32_bf16(kf0, qf, (f32x4){0.f, 0.f, 0.f, 0.f}, 0, 0, 0);
    f32x4 c1 = __builtin_amdgcn_mfma_f32_16x16x32_bf16(kf1, qf, (f32x4){0.f, 0.f, 0.f, 0.f}, 0, 0, 0);
    float p00 = exp2f(c0[0]), p01 = exp2f(c0[1]), p02 = exp2f(c0[2]), p03 = exp2f(c0[3]);
    float p10 = exp2f(c1[0]), p11 = exp2f(c1[1]), p12 = exp2f(c1[2]), p13 = exp2f(c1[3]);
    int base = j * 20;
    uint2 w0 = {bfpk(p00, p01), bfpk(p02, p03)};
    uint2 w1 = {bfpk(p10, p11), bfpk(p12, p13)};
    *reinterpret_cast<uint2*>(&plds[base + 2 * g])     = w0;
    *reinterpret_cast<uint2*>(&plds[base + 8 + 2 * g]) = w1;
    short8_t pf = *reinterpret_cast<const short8_t*>(&plds[base + 4 * g]);
    short8_t vf = *reinterpret_cast<const short8_t*>(vtbb + j * NN + M + 8 * g);
    acc = __builtin_amdgcn_mfma_f32_16x16x32_bf16(vf, pf, acc, 0, 0, 0);
}

// K4: xr + t + GN partials.  grid (NN/16, NB), 256 thr; 4-deep pipeline:
// 4 plds buffers + 2 independent accumulators.
__global__ __launch_bounds__(256) void k_xr(
    const unsigned short* __restrict__ qb, const unsigned short* __restrict__ kb,
    const unsigned short* __restrict__ vtb, const float* __restrict__ q,
    const float* __restrict__ w_t, const float* __restrict__ b_t,
    float* __restrict__ t, float* __restrict__ gnacc)
{
    __shared__ __align__(16) unsigned int plds_all[4][4][320];
    __shared__ float xls[4][64][5];
    __shared__ float pt[4][17][16];
    int lane = threadIdx.x & 63;
    int w = waveid();
    int j = lane & 15, g = lane >> 4;
    int b = blockIdx.y;
    int n0 = blockIdx.x * 16;

    short8_t qf = *reinterpret_cast<const short8_t*>(qb + ((size_t)(b * NN + n0 + j)) * 32 + 8 * g);
    const unsigned short* kbb  = kb  + (size_t)b * NN * 32;
    const unsigned short* vtbb = vtb + (size_t)b * DD * NN;

    f32x4 acc0 = {0.f, 0.f, 0.f, 0.f};
    f32x4 acc1 = {0.f, 0.f, 0.f, 0.f};
    for (int MC = w; MC < 128; MC += 16) {
        xr_body((MC)      * 32, plds_all[w][0], kbb, vtbb, qf, j, g, acc0);
        xr_body((MC + 4)  * 32, plds_all[w][1], kbb, vtbb, qf, j, g, acc1);
        xr_body((MC + 8)  * 32, plds_all[w][2], kbb, vtbb, qf, j, g, acc0);
        xr_body((MC + 12) * 32, plds_all[w][3], kbb, vtbb, qf, j, g, acc1);
    }
    f32x4 acc = acc0 + acc1;
#pragma unroll
    for (int r = 0; r < 4; ++r) xls[w][lane][r] = acc[r];
    __syncthreads();
    if (w == 0) {
        float4 tot;
        tot.x = xls[0][lane][0] + xls[1][lane][0] + xls[2][lane][0] + xls[3][lane][0];
        tot.y = xls[0][lane][1] + xls[1][lane][1] + xls[2][lane][1] + xls[3][lane][1];
        tot.z = xls[0][lane][2] + xls[1][lane][2] + xls[2][lane][2] + xls[3][lane][2];
        tot.w = xls[0][lane][3] + xls[1][lane][3] + xls[2][lane][3] + xls[3][lane][3];
        size_t row = (size_t)b * NN + n0 + j;
        const float4 q4 = *reinterpret_cast<const float4*>(q + row * DD + 4 * g);
        float d0 = q4.x - tot.x, d1 = q4.y - tot.y, d2 = q4.z - tot.z, d3 = q4.w - tot.w;
#pragma unroll
        for (int o = 0; o < DD; ++o) {
            const float4 wt = *reinterpret_cast<const float4*>(w_t + o * DD + 4 * g);
            pt[g][o][j] = wt.x * d0 + wt.y * d1 + wt.z * d2 + wt.w * d3;
        }
        __builtin_amdgcn_s_waitcnt(0);   // lgkmcnt(0): same-wave LDS ordering
        const float4 bt4 = *reinterpret_cast<const float4*>(b_t + 4 * g);
        float tq[4];
#pragma unroll
        for (int i = 0; i < 4; ++i) {
            int o = 4 * g + i;
            tq[i] = pt[0][o][j] + pt[1][o][j] + pt[2][o][j] + pt[3][o][j];
        }
        tq[0] += bt4.x; tq[1] += bt4.y; tq[2] += bt4.z; tq[3] += bt4.w;
        float4 tout = {tq[0], tq[1], tq[2], tq[3]};
        *reinterpret_cast<float4*>(t + row * DD + 4 * g) = tout;
        float s  = tq[0] + tq[1] + tq[2] + tq[3];
        float sq = tq[0]*tq[0] + tq[1]*tq[1] + tq[2]*tq[2] + tq[3]*tq[3];
#pragma unroll
        for (int dlt = 1; dlt < 16; dlt <<= 1) {
            s  += __shfl_xor(s, dlt);
            sq += __shfl_xor(sq, dlt);
        }
        if (j == 0) {
            atomicAdd(&gnacc[(b * GG + g) * 2 + 0], s);
            atomicAdd(&gnacc[(b * GG + g) * 2 + 1], sq);
        }
    }
}

// K5: out = q + relu(gn(t)), LDS-transposed stores. grid NB*NN/64 = 256 blocks.
__global__ __launch_bounds__(256) void k_out(
    const float* __restrict__ q, const float* __restrict__ t,
    const float* __restrict__ gnacc, const float* __restrict__ gamma,
    const float* __restrict__ beta, float* __restrict__ out)
{
    __shared__ float tl[64][17], ql[64][17];
    int tid = threadIdx.x;
    int g0 = blockIdx.x * 64;          // row base (b*NN + n)
    int b = g0 >> 12;

    {
        float4 tv = *reinterpret_cast<const float4*>(t + (size_t)g0 * DD + tid * 4);
        float4 qv = *reinterpret_cast<const float4*>(q + (size_t)g0 * DD + tid * 4);
        int r = (tid * 4) >> 4, c = (tid * 4) & 15;
        tl[r][c] = tv.x; tl[r][c + 1] = tv.y; tl[r][c + 2] = tv.z; tl[r][c + 3] = tv.w;
        ql[r][c] = qv.x; ql[r][c + 1] = qv.y; ql[r][c + 2] = qv.z; ql[r][c + 3] = qv.w;
    }
    __syncthreads();

    int o = tid >> 4, n16 = tid & 15;
    int g = o >> 2;
    const float cnt = 1.0f / (4.0f * NN);
    float ms = gnacc[(b * GG + g) * 2 + 0];
    float sqs = gnacc[(b * GG + g) * 2 + 1];
    float mean = ms * cnt;
    float var = sqs * cnt - mean * mean;
    float rsig = rsqrtf(var + EPSGN);
    float ga = gamma[o], be = beta[o];

    int r0 = n16 * 4;
    float4 res;
    res.x = ql[r0    ][o] + fmaxf((tl[r0    ][o] - mean) * rsig * ga + be, 0.f);
    res.y = ql[r0 + 1][o] + fmaxf((tl[r0 + 1][o] - mean) * rsig * ga + be, 0.f);
    res.z = ql[r0 + 2][o] + fmaxf((tl[r0 + 2][o] - mean) * rsig * ga + be, 0.f);
    res.w = ql[r0 + 3][o] + fmaxf((tl[r0 + 3][o] - mean) * rsig * ga + be, 0.f);
    *reinterpret_cast<float4*>(out + ((size_t)(b * DD + o)) * NN + (g0 & (NN - 1)) + r0) = res;
}

extern "C" void kernel_launch(void* const* d_in, const int* in_sizes, int n_in,
                              void* d_out, int out_size, void* d_ws, size_t ws_size,
                              hipStream_t stream)
{
    const float* x_q      = (const float*)d_in[0];
    const float* x_kv     = (const float*)d_in[1];
    const float* xyz_q    = (const float*)d_in[2];
    const float* xyz_kv   = (const float*)d_in[3];
    const float* w_qk     = (const float*)d_in[4];
    const float* w_v      = (const float*)d_in[5];
    const float* b_v      = (const float*)d_in[6];
    const float* w_t      = (const float*)d_in[7];
    const float* b_t      = (const float*)d_in[8];
    const float* gamma    = (const float*)d_in[9];
    const float* beta     = (const float*)d_in[10];
    const float* w_pos_q  = (const float*)d_in[11];
    const float* w_pos_kv = (const float*)d_in[12];

    float* ws = (float*)d_ws;
    float* q       = ws + OFF_Q;
    float* t       = ws + OFF_T;
    float* gnacc   = ws + OFF_GN;
    unsigned short* qb  = (unsigned short*)(ws + OFF_QB);
    unsigned short* kb  = (unsigned short*)(ws + OFF_KB);
    unsigned short* vtb = (unsigned short*)(ws + OFF_VTB);
    float* out     = (float*)d_out;

    k_qkv<<<dim3(NB * NN / 64), 512, 0, stream>>>(
        x_q, x_kv, xyz_q, xyz_kv, w_qk, w_v, b_v, w_pos_q, w_pos_kv,
        q, qb, kb, vtb, gnacc);

    k_rows<<<dim3(NN / 32, NB), 512, 0, stream>>>(qb, kb);
    k_cols<<<dim3(NN / 16, NB), 256, 0, stream>>>(qb, kb);
    k_xr<<<dim3(NN / 16, NB), 256, 0, stream>>>(qb, kb, vtb, q, w_t, b_t, t, gnacc);
    k_out<<<dim3(NB * NN / 64), 256, 0, stream>>>(q, t, gnacc, gamma, beta, out);
}

// Round 10
// 155.756 us; speedup vs baseline: 1.1879x; 1.1879x over previous
//
#include <hip/hip_runtime.h>
#include <hip/hip_bf16.h>

#define NB 4
#define CIN 128
#define NN 4096
#define DD 16
#define GG 4
#define EPSGN 1e-5f
#define L2E 1.4426950408889634f

typedef __attribute__((ext_vector_type(8))) short short8_t;
typedef __attribute__((ext_vector_type(4))) float f32x4;
typedef __attribute__((ext_vector_type(16))) float f32x16;

// ---------------- workspace layout (float slots) ----------------
#define OFF_Q      0          // q f32 [b][n][16]       262144
#define OFF_T      262144     // t f32 [b][n][o]        262144
#define OFF_GN     524288     // f32 [b][g][2]          32 (pad to 524320)
#define OFF_QB     524320     // bf16 [b][n][32]: d0..15 = q, 16..17 = lri2 hi/lo, 18..19 = 1,1
#define OFF_KB     786464     // bf16 [b][m][32]: d0..15 = k*log2e, 16..17 = 1,1, 18..19 = lci2 hi/lo
#define OFF_VTB    1048608    // bf16 [b][d][4096]      131072 slots
// total 1179680 floats = 4.72 MB

static __device__ __forceinline__ int waveid() {
    return __builtin_amdgcn_readfirstlane((int)(threadIdx.x >> 6));
}
static __device__ __forceinline__ unsigned int bfpk(float a, float b) {
    union { __hip_bfloat162 h2; unsigned int u; } c;
    c.h2 = __float22bfloat162_rn(float2{a, b});
    return c.u;
}
static __device__ __forceinline__ unsigned short bf1(float a) {
    union { __hip_bfloat16 h1; unsigned short u; } c;
    c.h1 = __float2bfloat16(a);
    return c.u;
}
// raw v_exp_f32 (2^x) via compiler-visible intrinsic: no ocml fixups,
// and the backend handles the trans-op wait-state hazard (unlike inline asm).
static __device__ __forceinline__ float aexp2(float x) {
    return __builtin_amdgcn_exp2f(x);
}

// K1: 1x1 convs + positional terms -> q (f32), qb/kb (bf16; k scaled by log2e),
// vtb (bf16 transposed [b][d][n]).  512 thr = 8 waves, 3-stage LDS tree.
__global__ __launch_bounds__(512) void k_qkv(
    const float* __restrict__ x_q, const float* __restrict__ x_kv,
    const float* __restrict__ xyz_q, const float* __restrict__ xyz_kv,
    const float* __restrict__ w_qk, const float* __restrict__ w_v,
    const float* __restrict__ b_v, const float* __restrict__ w_pos_q,
    const float* __restrict__ w_pos_kv,
    float* __restrict__ q, unsigned short* __restrict__ qb,
    unsigned short* __restrict__ kb, unsigned short* __restrict__ vtb,
    float* __restrict__ gnacc)
{
    __shared__ float part[4][64][49];
    int lane = threadIdx.x & 63;
    int w = waveid();                  // 0..7
    int g0 = blockIdx.x * 64;          // b*NN + n base
    int b = g0 >> 12;
    int n = (g0 & (NN - 1)) + lane;

    if (blockIdx.x == 0 && threadIdx.x < 32) gnacc[threadIdx.x] = 0.f;

    const float* xq = x_q  + (size_t)b * CIN * NN + n;
    const float* xk = x_kv + (size_t)b * CIN * NN + n;

    float aq[DD], ak[DD], av[DD];
#pragma unroll
    for (int d = 0; d < DD; ++d) { aq[d] = 0.f; ak[d] = 0.f; av[d] = 0.f; }

    for (int ci = 0; ci < 16; ++ci) {
        int c = w * 16 + ci;
        float vq = xq[(size_t)c * NN];
        float vk = xk[(size_t)c * NN];
#pragma unroll
        for (int d = 0; d < DD; ++d) {
            float wq = w_qk[d * CIN + c];            // uniform -> scalar
            aq[d] = fmaf(wq, vq, aq[d]);
            ak[d] = fmaf(wq, vk, ak[d]);
            av[d] = fmaf(w_v[d * CIN + c], vk, av[d]);
        }
    }

    if (w >= 4) {
#pragma unroll
        for (int d = 0; d < DD; ++d) {
            part[w - 4][lane][d]      = aq[d];
            part[w - 4][lane][d + 16] = ak[d];
            part[w - 4][lane][d + 32] = av[d];
        }
    }
    __syncthreads();
    if (w < 4) {
#pragma unroll
        for (int d = 0; d < DD; ++d) {
            aq[d] += part[w][lane][d];
            ak[d] += part[w][lane][d + 16];
            av[d] += part[w][lane][d + 32];
        }
    }
    __syncthreads();
    if (w == 2 || w == 3) {
#pragma unroll
        for (int d = 0; d < DD; ++d) {
            part[w - 2][lane][d]      = aq[d];
            part[w - 2][lane][d + 16] = ak[d];
            part[w - 2][lane][d + 32] = av[d];
        }
    }
    __syncthreads();
    if (w < 2) {
#pragma unroll
        for (int d = 0; d < DD; ++d) {
            aq[d] += part[w][lane][d];
            ak[d] += part[w][lane][d + 16];
            av[d] += part[w][lane][d + 32];
        }
    }
    __syncthreads();
    if (w == 1) {
#pragma unroll
        for (int d = 0; d < DD; ++d) {
            part[0][lane][d]      = aq[d];
            part[0][lane][d + 16] = ak[d];
            part[0][lane][d + 32] = av[d];
        }
    }
    __syncthreads();
    if (w == 0) {
#pragma unroll
        for (int d = 0; d < DD; ++d) {
            aq[d] += part[0][lane][d];
            ak[d] += part[0][lane][d + 16];
            av[d] += part[0][lane][d + 32];
        }
        float pq0 = xyz_q[((size_t)b * 3 + 0) * NN + n];
        float pq1 = xyz_q[((size_t)b * 3 + 1) * NN + n];
        float pq2 = xyz_q[((size_t)b * 3 + 2) * NN + n];
        float pk0 = xyz_kv[((size_t)b * 3 + 0) * NN + n];
        float pk1 = xyz_kv[((size_t)b * 3 + 1) * NN + n];
        float pk2 = xyz_kv[((size_t)b * 3 + 2) * NN + n];
        size_t row = (size_t)g0 + lane;
        float qv[DD], kv[DD];
#pragma unroll
        for (int d = 0; d < DD; ++d) {
            float posq = w_pos_q[d * 3] * pq0 + w_pos_q[d * 3 + 1] * pq1 + w_pos_q[d * 3 + 2] * pq2;
            float posk = w_pos_kv[d * 3] * pk0 + w_pos_kv[d * 3 + 1] * pk1 + w_pos_kv[d * 3 + 2] * pk2;
            qv[d] = aq[d] + posq;
            kv[d] = (ak[d] + posk) * L2E;            // exp2 domain
            q[row * DD + d] = qv[d];
            vtb[((size_t)(b * DD + d)) * NN + n] = bf1(av[d] + b_v[d] + posk);
        }
        unsigned int* qbw = (unsigned int*)(qb + row * 32);
        unsigned int* kbw = (unsigned int*)(kb + row * 32);
#pragma unroll
        for (int h = 0; h < 8; ++h) {
            qbw[h] = bfpk(qv[2 * h], qv[2 * h + 1]);
            kbw[h] = bfpk(kv[2 * h], kv[2 * h + 1]);
        }
        qbw[8] = 0u;                 // lri2 slot (k_rows writes)
        qbw[9] = bfpk(1.f, 1.f);     // picks up lci2 from kb[18..19]
        kbw[8] = bfpk(1.f, 1.f);     // picks up lri2 from qb[16..17]
        kbw[9] = 0u;                 // lci2 slot (k_cols writes)
#pragma unroll
        for (int h = 10; h < 16; ++h) { qbw[h] = 0u; kbw[h] = 0u; }
    }
}

// K2: rowsum via swapped 32x32x16 MFMA (K=16, pads unread): D[m][n], n=lane&31.
// rowsum = sum 2^s; writes lri2 = -log2(rowsum) into qb[n][16..17].
// grid (NN/32, NB), block 512; dual accumulation chains.
__global__ __launch_bounds__(512) void k_rows(
    unsigned short* __restrict__ qb, const unsigned short* __restrict__ kb)
{
    __shared__ float red[8][32];
    int lane = threadIdx.x & 63;
    int w = waveid();
    int l31 = lane & 31, h = lane >> 5;
    int b = blockIdx.y;
    int n0 = blockIdx.x * 32;

    unsigned short* qbb = qb + (size_t)b * NN * 32;
    const unsigned short* kbb = kb + (size_t)b * NN * 32;
    short8_t qf = *reinterpret_cast<const short8_t*>(qbb + (n0 + l31) * 32 + 8 * h);

    const f32x16 z16 = {0.f,0.f,0.f,0.f,0.f,0.f,0.f,0.f,0.f,0.f,0.f,0.f,0.f,0.f,0.f,0.f};
    float rs0 = 0.f, rs1 = 0.f;
    for (int mt = w; mt < 128; mt += 16) {
        short8_t kf0 = *reinterpret_cast<const short8_t*>(kbb + ((mt) * 32 + l31) * 32 + 8 * h);
        short8_t kf1 = *reinterpret_cast<const short8_t*>(kbb + ((mt + 8) * 32 + l31) * 32 + 8 * h);
        f32x16 c0 = __builtin_amdgcn_mfma_f32_32x32x16_bf16(kf0, qf, z16, 0, 0, 0);
        f32x16 c1 = __builtin_amdgcn_mfma_f32_32x32x16_bf16(kf1, qf, z16, 0, 0, 0);
#pragma unroll
        for (int r = 0; r < 16; ++r) rs0 += aexp2(c0[r]);
#pragma unroll
        for (int r = 0; r < 16; ++r) rs1 += aexp2(c1[r]);
    }
    float rs = rs0 + rs1;
    rs += __shfl_xor(rs, 32);
    if (lane < 32) red[w][l31] = rs;
    __syncthreads();
    if (threadIdx.x < 32) {
        float s = 0.f;
#pragma unroll
        for (int ww = 0; ww < 8; ++ww) s += red[ww][threadIdx.x];
        float lri = -log2f(s);
        float hi = __bfloat162float(__float2bfloat16(lri));
        *(unsigned int*)(qbb + (n0 + threadIdx.x) * 32 + 16) = bfpk(lri, lri - hi);
    }
}

// K3: colsum via non-swapped 16x16x32 MFMA, K=32 incl. pads (e' = s + lri2).
// 2 kf tiles per wave (32 m/block), qf loads shared; 4 chains.
// cs = sum_n 2^e'; writes lci2 = -log2(1e-9+cs) into kb[m][18..19].
// grid (NN/32, NB), block 256.
__global__ __launch_bounds__(256, 4) void k_cols(
    const unsigned short* __restrict__ qb, unsigned short* __restrict__ kb)
{
    __shared__ float red[4][32];
    int lane = threadIdx.x & 63;
    int w = waveid();
    int j = lane & 15, g = lane >> 4;
    int b = blockIdx.y;
    int m0 = blockIdx.x * 32;

    unsigned short* kbb = kb + (size_t)b * NN * 32;
    const unsigned short* qbb = qb + (size_t)b * NN * 32;
    short8_t kf0 = *reinterpret_cast<const short8_t*>(kbb + (m0 + j) * 32 + 8 * g);
    short8_t kf1 = *reinterpret_cast<const short8_t*>(kbb + (m0 + 16 + j) * 32 + 8 * g);

    float cs00 = 0.f, cs01 = 0.f, cs10 = 0.f, cs11 = 0.f;
    for (int nt = w; nt < 256; nt += 8) {
        short8_t qf0 = *reinterpret_cast<const short8_t*>(qbb + ((nt) * 16 + j) * 32 + 8 * g);
        short8_t qf1 = *reinterpret_cast<const short8_t*>(qbb + ((nt + 4) * 16 + j) * 32 + 8 * g);
        f32x4 c00 = __builtin_amdgcn_mfma_f32_16x16x32_bf16(qf0, kf0, (f32x4){0.f, 0.f, 0.f, 0.f}, 0, 0, 0);
        f32x4 c01 = __builtin_amdgcn_mfma_f32_16x16x32_bf16(qf0, kf1, (f32x4){0.f, 0.f, 0.f, 0.f}, 0, 0, 0);
        f32x4 c10 = __builtin_amdgcn_mfma_f32_16x16x32_bf16(qf1, kf0, (f32x4){0.f, 0.f, 0.f, 0.f}, 0, 0, 0);
        f32x4 c11 = __builtin_amdgcn_mfma_f32_16x16x32_bf16(qf1, kf1, (f32x4){0.f, 0.f, 0.f, 0.f}, 0, 0, 0);
        cs00 += aexp2(c00[0]) + aexp2(c00[1]) + aexp2(c00[2]) + aexp2(c00[3]);
        cs01 += aexp2(c01[0]) + aexp2(c01[1]) + aexp2(c01[2]) + aexp2(c01[3]);
        cs10 += aexp2(c10[0]) + aexp2(c10[1]) + aexp2(c10[2]) + aexp2(c10[3]);
        cs11 += aexp2(c11[0]) + aexp2(c11[1]) + aexp2(c11[2]) + aexp2(c11[3]);
    }
    float csA = cs00 + cs10;   // m = m0 + j
    float csB = cs01 + cs11;   // m = m0 + 16 + j
    csA += __shfl_xor(csA, 16); csA += __shfl_xor(csA, 32);
    csB += __shfl_xor(csB, 16); csB += __shfl_xor(csB, 32);
    if (lane < 16) { red[w][lane] = csA; red[w][lane + 16] = csB; }
    __syncthreads();
    if (threadIdx.x < 32) {
        float s = red[0][threadIdx.x] + red[1][threadIdx.x] + red[2][threadIdx.x] + red[3][threadIdx.x];
        float lci = -log2f(1e-9f + s);
        float hi = __bfloat162float(__float2bfloat16(lci));
        *(unsigned int*)(kbb + (m0 + threadIdx.x) * 32 + 18) = bfpk(lci, lci - hi);
    }
}

// K4: xr + t + GN partials.  32-n per block (2 qf chains/wave), 512 thr,
// 8-wave m-split; kf/vf shared across the 2 chains.  grid (NN/32, NB).
__global__ __launch_bounds__(512, 4) void k_xr(
    const unsigned short* __restrict__ qb, const unsigned short* __restrict__ kb,
    const unsigned short* __restrict__ vtb, const float* __restrict__ q,
    const float* __restrict__ w_t, const float* __restrict__ b_t,
    float* __restrict__ t, float* __restrict__ gnacc)
{
    __shared__ __align__(16) unsigned int plds[8][2][320];   // 20.0 KB
    __shared__ float xls[8][2][64][5];                        // 20.0 KB
    __shared__ float pt[2][4][17][16];                        // 8.7 KB
    int lane = threadIdx.x & 63;
    int w = waveid();                  // 0..7
    int j = lane & 15, g = lane >> 4;
    int b = blockIdx.y;
    int n0 = blockIdx.x * 32;

    const unsigned short* qbb  = qb  + (size_t)b * NN * 32;
    const unsigned short* kbb  = kb  + (size_t)b * NN * 32;
    const unsigned short* vtbb = vtb + (size_t)b * DD * NN;
    short8_t qf0 = *reinterpret_cast<const short8_t*>(qbb + (n0 + j) * 32 + 8 * g);
    short8_t qf1 = *reinterpret_cast<const short8_t*>(qbb + (n0 + 16 + j) * 32 + 8 * g);

    f32x4 acc0 = {0.f, 0.f, 0.f, 0.f};
    f32x4 acc1 = {0.f, 0.f, 0.f, 0.f};
    unsigned int* p0 = plds[w][0];
    unsigned int* p1 = plds[w][1];
#pragma unroll 2
    for (int MC = w; MC < 128; MC += 8) {
        int M = MC * 32;
        short8_t kf0 = *reinterpret_cast<const short8_t*>(kbb + (M + j) * 32 + 8 * g);
        short8_t kf1 = *reinterpret_cast<const short8_t*>(kbb + (M + 16 + j) * 32 + 8 * g);
        short8_t vf  = *reinterpret_cast<const short8_t*>(vtbb + j * NN + M + 8 * g);
        f32x4 c00 = __builtin_amdgcn_mfma_f32_16x16x32_bf16(kf0, qf0, (f32x4){0.f, 0.f, 0.f, 0.f}, 0, 0, 0);
        f32x4 c01 = __builtin_amdgcn_mfma_f32_16x16x32_bf16(kf1, qf0, (f32x4){0.f, 0.f, 0.f, 0.f}, 0, 0, 0);
        f32x4 c10 = __builtin_amdgcn_mfma_f32_16x16x32_bf16(kf0, qf1, (f32x4){0.f, 0.f, 0.f, 0.f}, 0, 0, 0);
        f32x4 c11 = __builtin_amdgcn_mfma_f32_16x16x32_bf16(kf1, qf1, (f32x4){0.f, 0.f, 0.f, 0.f}, 0, 0, 0);
        int base = j * 20;
        {   // chain 0 (n-subtile 0)
            uint2 w0 = {bfpk(aexp2(c00[0]), aexp2(c00[1])), bfpk(aexp2(c00[2]), aexp2(c00[3]))};
            uint2 w1 = {bfpk(aexp2(c01[0]), aexp2(c01[1])), bfpk(aexp2(c01[2]), aexp2(c01[3]))};
            *reinterpret_cast<uint2*>(&p0[base + 2 * g])     = w0;
            *reinterpret_cast<uint2*>(&p0[base + 8 + 2 * g]) = w1;
        }
        {   // chain 1 (n-subtile 1)
            uint2 w0 = {bfpk(aexp2(c10[0]), aexp2(c10[1])), bfpk(aexp2(c10[2]), aexp2(c10[3]))};
            uint2 w1 = {bfpk(aexp2(c11[0]), aexp2(c11[1])), bfpk(aexp2(c11[2]), aexp2(c11[3]))};
            *reinterpret_cast<uint2*>(&p1[base + 2 * g])     = w0;
            *reinterpret_cast<uint2*>(&p1[base + 8 + 2 * g]) = w1;
        }
        short8_t pf0 = *reinterpret_cast<const short8_t*>(&p0[base + 4 * g]);
        short8_t pf1 = *reinterpret_cast<const short8_t*>(&p1[base + 4 * g]);
        acc0 = __builtin_amdgcn_mfma_f32_16x16x32_bf16(vf, pf0, acc0, 0, 0, 0);
        acc1 = __builtin_amdgcn_mfma_f32_16x16x32_bf16(vf, pf1, acc1, 0, 0, 0);
    }
#pragma unroll
    for (int r = 0; r < 4; ++r) {
        xls[w][0][lane][r] = acc0[r];
        xls[w][1][lane][r] = acc1[r];
    }
    __syncthreads();
    if (w < 2) {                         // wave w owns n-subtile nt = w
        int nt = w;
        float tot[4];
#pragma unroll
        for (int r = 0; r < 4; ++r) {
            float s = 0.f;
#pragma unroll
            for (int ww = 0; ww < 8; ++ww) s += xls[ww][nt][lane][r];
            tot[r] = s;
        }
        size_t row = (size_t)b * NN + n0 + nt * 16 + j;
        const float4 q4 = *reinterpret_cast<const float4*>(q + row * DD + 4 * g);
        float d0 = q4.x - tot[0], d1 = q4.y - tot[1], d2 = q4.z - tot[2], d3 = q4.w - tot[3];
#pragma unroll
        for (int o = 0; o < DD; ++o) {
            const float4 wt = *reinterpret_cast<const float4*>(w_t + o * DD + 4 * g);
            pt[nt][g][o][j] = wt.x * d0 + wt.y * d1 + wt.z * d2 + wt.w * d3;
        }
        __builtin_amdgcn_s_waitcnt(0);   // lgkmcnt(0): same-wave LDS ordering
        const float4 bt4 = *reinterpret_cast<const float4*>(b_t + 4 * g);
        float tq[4];
#pragma unroll
        for (int i = 0; i < 4; ++i) {
            int o = 4 * g + i;
            tq[i] = pt[nt][0][o][j] + pt[nt][1][o][j] + pt[nt][2][o][j] + pt[nt][3][o][j];
        }
        tq[0] += bt4.x; tq[1] += bt4.y; tq[2] += bt4.z; tq[3] += bt4.w;
        float4 tout = {tq[0], tq[1], tq[2], tq[3]};
        *reinterpret_cast<float4*>(t + row * DD + 4 * g) = tout;
        float s  = tq[0] + tq[1] + tq[2] + tq[3];
        float sq = tq[0]*tq[0] + tq[1]*tq[1] + tq[2]*tq[2] + tq[3]*tq[3];
#pragma unroll
        for (int dlt = 1; dlt < 16; dlt <<= 1) {
            s  += __shfl_xor(s, dlt);
            sq += __shfl_xor(sq, dlt);
        }
        if (j == 0) {
            atomicAdd(&gnacc[(b * GG + g) * 2 + 0], s);
            atomicAdd(&gnacc[(b * GG + g) * 2 + 1], sq);
        }
    }
}

// K5: out = q + relu(gn(t)), LDS-transposed stores. grid NB*NN/64 = 256 blocks.
__global__ __launch_bounds__(256) void k_out(
    const float* __restrict__ q, const float* __restrict__ t,
    const float* __restrict__ gnacc, const float* __restrict__ gamma,
    const float* __restrict__ beta, float* __restrict__ out)
{
    __shared__ float tl[64][17], ql[64][17];
    int tid = threadIdx.x;
    int g0 = blockIdx.x * 64;          // row base (b*NN + n)
    int b = g0 >> 12;

    {
        float4 tv = *reinterpret_cast<const float4*>(t + (size_t)g0 * DD + tid * 4);
        float4 qv = *reinterpret_cast<const float4*>(q + (size_t)g0 * DD + tid * 4);
        int r = (tid * 4) >> 4, c = (tid * 4) & 15;
        tl[r][c] = tv.x; tl[r][c + 1] = tv.y; tl[r][c + 2] = tv.z; tl[r][c + 3] = tv.w;
        ql[r][c] = qv.x; ql[r][c + 1] = qv.y; ql[r][c + 2] = qv.z; ql[r][c + 3] = qv.w;
    }
    __syncthreads();

    int o = tid >> 4, n16 = tid & 15;
    int g = o >> 2;
    const float cnt = 1.0f / (4.0f * NN);
    float ms = gnacc[(b * GG + g) * 2 + 0];
    float sqs = gnacc[(b * GG + g) * 2 + 1];
    float mean = ms * cnt;
    float var = sqs * cnt - mean * mean;
    float rsig = rsqrtf(var + EPSGN);
    float ga = gamma[o], be = beta[o];

    int r0 = n16 * 4;
    float4 res;
    res.x = ql[r0    ][o] + fmaxf((tl[r0    ][o] - mean) * rsig * ga + be, 0.f);
    res.y = ql[r0 + 1][o] + fmaxf((tl[r0 + 1][o] - mean) * rsig * ga + be, 0.f);
    res.z = ql[r0 + 2][o] + fmaxf((tl[r0 + 2][o] - mean) * rsig * ga + be, 0.f);
    res.w = ql[r0 + 3][o] + fmaxf((tl[r0 + 3][o] - mean) * rsig * ga + be, 0.f);
    *reinterpret_cast<float4*>(out + ((size_t)(b * DD + o)) * NN + (g0 & (NN - 1)) + r0) = res;
}

extern "C" void kernel_launch(void* const* d_in, const int* in_sizes, int n_in,
                              void* d_out, int out_size, void* d_ws, size_t ws_size,
                              hipStream_t stream)
{
    const float* x_q      = (const float*)d_in[0];
    const float* x_kv     = (const float*)d_in[1];
    const float* xyz_q    = (const float*)d_in[2];
    const float* xyz_kv   = (const float*)d_in[3];
    const float* w_qk     = (const float*)d_in[4];
    const float* w_v      = (const float*)d_in[5];
    const float* b_v      = (const float*)d_in[6];
    const float* w_t      = (const float*)d_in[7];
    const float* b_t      = (const float*)d_in[8];
    const float* gamma    = (const float*)d_in[9];
    const float* beta     = (const float*)d_in[10];
    const float* w_pos_q  = (const float*)d_in[11];
    const float* w_pos_kv = (const float*)d_in[12];

    float* ws = (float*)d_ws;
    float* q       = ws + OFF_Q;
    float* t       = ws + OFF_T;
    float* gnacc   = ws + OFF_GN;
    unsigned short* qb  = (unsigned short*)(ws + OFF_QB);
    unsigned short* kb  = (unsigned short*)(ws + OFF_KB);
    unsigned short* vtb = (unsigned short*)(ws + OFF_VTB);
    float* out     = (float*)d_out;

    k_qkv<<<dim3(NB * NN / 64), 512, 0, stream>>>(
        x_q, x_kv, xyz_q, xyz_kv, w_qk, w_v, b_v, w_pos_q, w_pos_kv,
        q, qb, kb, vtb, gnacc);

    k_rows<<<dim3(NN / 32, NB), 512, 0, stream>>>(qb, kb);
    k_cols<<<dim3(NN / 32, NB), 256, 0, stream>>>(qb, kb);
    k_xr<<<dim3(NN / 32, NB), 512, 0, stream>>>(qb, kb, vtb, q, w_t, b_t, t, gnacc);
    k_out<<<dim3(NB * NN / 64), 256, 0, stream>>>(q, t, gnacc, gamma, beta, out);
}

// Round 11
// 153.759 us; speedup vs baseline: 1.2033x; 1.0130x over previous
//
#include <hip/hip_runtime.h>
#include <hip/hip_bf16.h>

#define NB 4
#define CIN 128
#define NN 4096
#define DD 16
#define GG 4
#define EPSGN 1e-5f
#define L2E 1.4426950408889634f

typedef __attribute__((ext_vector_type(8))) short short8_t;
typedef __attribute__((ext_vector_type(4))) float f32x4;
typedef __attribute__((ext_vector_type(16))) float f32x16;

// ---------------- workspace layout (float slots) ----------------
#define OFF_Q      0          // q f32 [b][n][16]       262144
#define OFF_T      262144     // t f32 [b][n][o]        262144
#define OFF_GN     524288     // f32 [b][g][2]          32 (pad to 524320)
#define OFF_QB     524320     // bf16 [b][n][32]: d0..15 = q, 16..17 = lri2 hi/lo, 18..19 = 1,1
#define OFF_KB     786464     // bf16 [b][m][32]: d0..15 = k*log2e, 16..17 = 1,1, 18..19 = lci2 hi/lo
#define OFF_VTB    1048608    // bf16 [b][d][4096]      131072 slots
// total 1179680 floats = 4.72 MB

static __device__ __forceinline__ int waveid() {
    return __builtin_amdgcn_readfirstlane((int)(threadIdx.x >> 6));
}
static __device__ __forceinline__ unsigned int bfpk(float a, float b) {
    union { __hip_bfloat162 h2; unsigned int u; } c;
    c.h2 = __float22bfloat162_rn(float2{a, b});
    return c.u;
}
static __device__ __forceinline__ unsigned short bf1(float a) {
    union { __hip_bfloat16 h1; unsigned short u; } c;
    c.h1 = __float2bfloat16(a);
    return c.u;
}
// raw v_exp_f32 (2^x) via compiler-visible intrinsic (hazards handled).
static __device__ __forceinline__ float aexp2(float x) {
    return __builtin_amdgcn_exp2f(x);
}

// K1: 1x1 convs + positional terms -> q (f32), qb/kb (bf16; k scaled by log2e),
// vtb (bf16 transposed [b][d][n]).  512 thr = 8 waves, 3-stage LDS tree.
__global__ __launch_bounds__(512) void k_qkv(
    const float* __restrict__ x_q, const float* __restrict__ x_kv,
    const float* __restrict__ xyz_q, const float* __restrict__ xyz_kv,
    const float* __restrict__ w_qk, const float* __restrict__ w_v,
    const float* __restrict__ b_v, const float* __restrict__ w_pos_q,
    const float* __restrict__ w_pos_kv,
    float* __restrict__ q, unsigned short* __restrict__ qb,
    unsigned short* __restrict__ kb, unsigned short* __restrict__ vtb,
    float* __restrict__ gnacc)
{
    __shared__ float part[4][64][49];
    int lane = threadIdx.x & 63;
    int w = waveid();                  // 0..7
    int g0 = blockIdx.x * 64;          // b*NN + n base
    int b = g0 >> 12;
    int n = (g0 & (NN - 1)) + lane;

    if (blockIdx.x == 0 && threadIdx.x < 32) gnacc[threadIdx.x] = 0.f;

    const float* xq = x_q  + (size_t)b * CIN * NN + n;
    const float* xk = x_kv + (size_t)b * CIN * NN + n;

    float aq[DD], ak[DD], av[DD];
#pragma unroll
    for (int d = 0; d < DD; ++d) { aq[d] = 0.f; ak[d] = 0.f; av[d] = 0.f; }

    for (int ci = 0; ci < 16; ++ci) {
        int c = w * 16 + ci;
        float vq = xq[(size_t)c * NN];
        float vk = xk[(size_t)c * NN];
#pragma unroll
        for (int d = 0; d < DD; ++d) {
            float wq = w_qk[d * CIN + c];            // uniform -> scalar
            aq[d] = fmaf(wq, vq, aq[d]);
            ak[d] = fmaf(wq, vk, ak[d]);
            av[d] = fmaf(w_v[d * CIN + c], vk, av[d]);
        }
    }

    if (w >= 4) {
#pragma unroll
        for (int d = 0; d < DD; ++d) {
            part[w - 4][lane][d]      = aq[d];
            part[w - 4][lane][d + 16] = ak[d];
            part[w - 4][lane][d + 32] = av[d];
        }
    }
    __syncthreads();
    if (w < 4) {
#pragma unroll
        for (int d = 0; d < DD; ++d) {
            aq[d] += part[w][lane][d];
            ak[d] += part[w][lane][d + 16];
            av[d] += part[w][lane][d + 32];
        }
    }
    __syncthreads();
    if (w == 2 || w == 3) {
#pragma unroll
        for (int d = 0; d < DD; ++d) {
            part[w - 2][lane][d]      = aq[d];
            part[w - 2][lane][d + 16] = ak[d];
            part[w - 2][lane][d + 32] = av[d];
        }
    }
    __syncthreads();
    if (w < 2) {
#pragma unroll
        for (int d = 0; d < DD; ++d) {
            aq[d] += part[w][lane][d];
            ak[d] += part[w][lane][d + 16];
            av[d] += part[w][lane][d + 32];
        }
    }
    __syncthreads();
    if (w == 1) {
#pragma unroll
        for (int d = 0; d < DD; ++d) {
            part[0][lane][d]      = aq[d];
            part[0][lane][d + 16] = ak[d];
            part[0][lane][d + 32] = av[d];
        }
    }
    __syncthreads();
    if (w == 0) {
#pragma unroll
        for (int d = 0; d < DD; ++d) {
            aq[d] += part[0][lane][d];
            ak[d] += part[0][lane][d + 16];
            av[d] += part[0][lane][d + 32];
        }
        float pq0 = xyz_q[((size_t)b * 3 + 0) * NN + n];
        float pq1 = xyz_q[((size_t)b * 3 + 1) * NN + n];
        float pq2 = xyz_q[((size_t)b * 3 + 2) * NN + n];
        float pk0 = xyz_kv[((size_t)b * 3 + 0) * NN + n];
        float pk1 = xyz_kv[((size_t)b * 3 + 1) * NN + n];
        float pk2 = xyz_kv[((size_t)b * 3 + 2) * NN + n];
        size_t row = (size_t)g0 + lane;
        float qv[DD], kv[DD];
#pragma unroll
        for (int d = 0; d < DD; ++d) {
            float posq = w_pos_q[d * 3] * pq0 + w_pos_q[d * 3 + 1] * pq1 + w_pos_q[d * 3 + 2] * pq2;
            float posk = w_pos_kv[d * 3] * pk0 + w_pos_kv[d * 3 + 1] * pk1 + w_pos_kv[d * 3 + 2] * pk2;
            qv[d] = aq[d] + posq;
            kv[d] = (ak[d] + posk) * L2E;            // exp2 domain
            q[row * DD + d] = qv[d];
            vtb[((size_t)(b * DD + d)) * NN + n] = bf1(av[d] + b_v[d] + posk);
        }
        unsigned int* qbw = (unsigned int*)(qb + row * 32);
        unsigned int* kbw = (unsigned int*)(kb + row * 32);
#pragma unroll
        for (int h = 0; h < 8; ++h) {
            qbw[h] = bfpk(qv[2 * h], qv[2 * h + 1]);
            kbw[h] = bfpk(kv[2 * h], kv[2 * h + 1]);
        }
        qbw[8] = 0u;                 // lri2 slot (k_rows writes)
        qbw[9] = bfpk(1.f, 1.f);     // picks up lci2 from kb[18..19]
        kbw[8] = bfpk(1.f, 1.f);     // picks up lri2 from qb[16..17]
        kbw[9] = 0u;                 // lci2 slot (k_cols writes)
#pragma unroll
        for (int h = 10; h < 16; ++h) { qbw[h] = 0u; kbw[h] = 0u; }
    }
}

// K2: rowsum via swapped 32x32x16 MFMA (K=16, pads unread): D[m][n], n=lane&31.
// rowsum = sum 2^s; writes lri2 = -log2(rowsum) into qb[n][16..17].
// grid (NN/32, NB), block 512; dual accumulation chains.
__global__ __launch_bounds__(512) void k_rows(
    unsigned short* __restrict__ qb, const unsigned short* __restrict__ kb)
{
    __shared__ float red[8][32];
    int lane = threadIdx.x & 63;
    int w = waveid();
    int l31 = lane & 31, h = lane >> 5;
    int b = blockIdx.y;
    int n0 = blockIdx.x * 32;

    unsigned short* qbb = qb + (size_t)b * NN * 32;
    const unsigned short* kbb = kb + (size_t)b * NN * 32;
    short8_t qf = *reinterpret_cast<const short8_t*>(qbb + (n0 + l31) * 32 + 8 * h);

    const f32x16 z16 = {0.f,0.f,0.f,0.f,0.f,0.f,0.f,0.f,0.f,0.f,0.f,0.f,0.f,0.f,0.f,0.f};
    float rs0 = 0.f, rs1 = 0.f;
    for (int mt = w; mt < 128; mt += 16) {
        short8_t kf0 = *reinterpret_cast<const short8_t*>(kbb + ((mt) * 32 + l31) * 32 + 8 * h);
        short8_t kf1 = *reinterpret_cast<const short8_t*>(kbb + ((mt + 8) * 32 + l31) * 32 + 8 * h);
        f32x16 c0 = __builtin_amdgcn_mfma_f32_32x32x16_bf16(kf0, qf, z16, 0, 0, 0);
        f32x16 c1 = __builtin_amdgcn_mfma_f32_32x32x16_bf16(kf1, qf, z16, 0, 0, 0);
#pragma unroll
        for (int r = 0; r < 16; ++r) rs0 += aexp2(c0[r]);
#pragma unroll
        for (int r = 0; r < 16; ++r) rs1 += aexp2(c1[r]);
    }
    float rs = rs0 + rs1;
    rs += __shfl_xor(rs, 32);
    if (lane < 32) red[w][l31] = rs;
    __syncthreads();
    if (threadIdx.x < 32) {
        float s = 0.f;
#pragma unroll
        for (int ww = 0; ww < 8; ++ww) s += red[ww][threadIdx.x];
        float lri = -log2f(s);
        float hi = __bfloat162float(__float2bfloat16(lri));
        *(unsigned int*)(qbb + (n0 + threadIdx.x) * 32 + 16) = bfpk(lri, lri - hi);
    }
}

// K3: colsum via non-swapped 16x16x32 MFMA, K=32 incl. pads (e' = s + lri2).
// 512 thr = 8 waves; 2 kf tiles/wave (32 m/block), qf loads shared; 4 chains.
// cs = sum_n 2^e'; writes lci2 = -log2(1e-9+cs) into kb[m][18..19].
// grid (NN/32, NB) = 512 blocks -> 16 waves/CU.
__global__ __launch_bounds__(512, 4) void k_cols(
    const unsigned short* __restrict__ qb, unsigned short* __restrict__ kb)
{
    __shared__ float red[8][32];
    int lane = threadIdx.x & 63;
    int w = waveid();                  // 0..7
    int j = lane & 15, g = lane >> 4;
    int b = blockIdx.y;
    int m0 = blockIdx.x * 32;

    unsigned short* kbb = kb + (size_t)b * NN * 32;
    const unsigned short* qbb = qb + (size_t)b * NN * 32;
    short8_t kf0 = *reinterpret_cast<const short8_t*>(kbb + (m0 + j) * 32 + 8 * g);
    short8_t kf1 = *reinterpret_cast<const short8_t*>(kbb + (m0 + 16 + j) * 32 + 8 * g);

    float cs00 = 0.f, cs01 = 0.f, cs10 = 0.f, cs11 = 0.f;
    for (int nt = w; nt < 256; nt += 16) {
        short8_t qf0 = *reinterpret_cast<const short8_t*>(qbb + ((nt) * 16 + j) * 32 + 8 * g);
        short8_t qf1 = *reinterpret_cast<const short8_t*>(qbb + ((nt + 8) * 16 + j) * 32 + 8 * g);
        f32x4 c00 = __builtin_amdgcn_mfma_f32_16x16x32_bf16(qf0, kf0, (f32x4){0.f, 0.f, 0.f, 0.f}, 0, 0, 0);
        f32x4 c01 = __builtin_amdgcn_mfma_f32_16x16x32_bf16(qf0, kf1, (f32x4){0.f, 0.f, 0.f, 0.f}, 0, 0, 0);
        f32x4 c10 = __builtin_amdgcn_mfma_f32_16x16x32_bf16(qf1, kf0, (f32x4){0.f, 0.f, 0.f, 0.f}, 0, 0, 0);
        f32x4 c11 = __builtin_amdgcn_mfma_f32_16x16x32_bf16(qf1, kf1, (f32x4){0.f, 0.f, 0.f, 0.f}, 0, 0, 0);
        cs00 += aexp2(c00[0]) + aexp2(c00[1]) + aexp2(c00[2]) + aexp2(c00[3]);
        cs01 += aexp2(c01[0]) + aexp2(c01[1]) + aexp2(c01[2]) + aexp2(c01[3]);
        cs10 += aexp2(c10[0]) + aexp2(c10[1]) + aexp2(c10[2]) + aexp2(c10[3]);
        cs11 += aexp2(c11[0]) + aexp2(c11[1]) + aexp2(c11[2]) + aexp2(c11[3]);
    }
    float csA = cs00 + cs10;   // m = m0 + j
    float csB = cs01 + cs11;   // m = m0 + 16 + j
    csA += __shfl_xor(csA, 16); csA += __shfl_xor(csA, 32);
    csB += __shfl_xor(csB, 16); csB += __shfl_xor(csB, 32);
    if (lane < 16) { red[w][lane] = csA; red[w][lane + 16] = csB; }
    __syncthreads();
    if (threadIdx.x < 32) {
        float s = 0.f;
#pragma unroll
        for (int ww = 0; ww < 8; ++ww) s += red[ww][threadIdx.x];
        float lci = -log2f(1e-9f + s);
        float hi = __bfloat162float(__float2bfloat16(lci));
        *(unsigned int*)(kbb + (m0 + threadIdx.x) * 32 + 18) = bfpk(lci, lci - hi);
    }
}

// K4 body: one 32-m chunk (both n-subtiles). e' = s + lri2 + lci2 via pads;
// P = 2^e' -> bf16 repack (LDS, b64 writes) -> 2 PV mfma accumulates.
static __device__ __forceinline__ void xr_body(
    int M, unsigned int* __restrict__ p0, unsigned int* __restrict__ p1,
    const unsigned short* __restrict__ kbb, const unsigned short* __restrict__ vtbb,
    short8_t qf0, short8_t qf1, int j, int g, f32x4& acc0, f32x4& acc1)
{
    short8_t kf0 = *reinterpret_cast<const short8_t*>(kbb + (M + j) * 32 + 8 * g);
    short8_t kf1 = *reinterpret_cast<const short8_t*>(kbb + (M + 16 + j) * 32 + 8 * g);
    short8_t vf  = *reinterpret_cast<const short8_t*>(vtbb + j * NN + M + 8 * g);
    f32x4 c00 = __builtin_amdgcn_mfma_f32_16x16x32_bf16(kf0, qf0, (f32x4){0.f, 0.f, 0.f, 0.f}, 0, 0, 0);
    f32x4 c01 = __builtin_amdgcn_mfma_f32_16x16x32_bf16(kf1, qf0, (f32x4){0.f, 0.f, 0.f, 0.f}, 0, 0, 0);
    f32x4 c10 = __builtin_amdgcn_mfma_f32_16x16x32_bf16(kf0, qf1, (f32x4){0.f, 0.f, 0.f, 0.f}, 0, 0, 0);
    f32x4 c11 = __builtin_amdgcn_mfma_f32_16x16x32_bf16(kf1, qf1, (f32x4){0.f, 0.f, 0.f, 0.f}, 0, 0, 0);
    int base = j * 20;
    {   // chain 0 (n-subtile 0)
        uint2 w0 = {bfpk(aexp2(c00[0]), aexp2(c00[1])), bfpk(aexp2(c00[2]), aexp2(c00[3]))};
        uint2 w1 = {bfpk(aexp2(c01[0]), aexp2(c01[1])), bfpk(aexp2(c01[2]), aexp2(c01[3]))};
        *reinterpret_cast<uint2*>(&p0[base + 2 * g])     = w0;
        *reinterpret_cast<uint2*>(&p0[base + 8 + 2 * g]) = w1;
    }
    {   // chain 1 (n-subtile 1)
        uint2 w0 = {bfpk(aexp2(c10[0]), aexp2(c10[1])), bfpk(aexp2(c10[2]), aexp2(c10[3]))};
        uint2 w1 = {bfpk(aexp2(c11[0]), aexp2(c11[1])), bfpk(aexp2(c11[2]), aexp2(c11[3]))};
        *reinterpret_cast<uint2*>(&p1[base + 2 * g])     = w0;
        *reinterpret_cast<uint2*>(&p1[base + 8 + 2 * g]) = w1;
    }
    short8_t pf0 = *reinterpret_cast<const short8_t*>(&p0[base + 4 * g]);
    short8_t pf1 = *reinterpret_cast<const short8_t*>(&p1[base + 4 * g]);
    acc0 = __builtin_amdgcn_mfma_f32_16x16x32_bf16(vf, pf0, acc0, 0, 0, 0);
    acc1 = __builtin_amdgcn_mfma_f32_16x16x32_bf16(vf, pf1, acc1, 0, 0, 0);
}

// K4: xr + t + GN partials.  32-n per block (2 qf chains/wave), 512 thr,
// 8-wave m-split; 2-deep buffer rotation (4 plds buffers/wave) removes the
// LDS WAR serialization between consecutive iterations.  plds is UNION'd
// with the epilogue scratch (xls/pt) -> extra barrier after the main loop.
// grid (NN/32, NB).
__global__ __launch_bounds__(512, 4) void k_xr(
    const unsigned short* __restrict__ qb, const unsigned short* __restrict__ kb,
    const unsigned short* __restrict__ vtb, const float* __restrict__ q,
    const float* __restrict__ w_t, const float* __restrict__ b_t,
    float* __restrict__ t, float* __restrict__ gnacc)
{
    __shared__ __align__(16) char smem[40960];               // 40 KB union
    unsigned int (*plds)[4][320] = reinterpret_cast<unsigned int(*)[4][320]>(smem); // [8][4][320]
    float (*xls)[2][64][5] = reinterpret_cast<float(*)[2][64][5]>(smem);            // [8][2][64][5] @0
    float (*pt)[4][17][16] = reinterpret_cast<float(*)[4][17][16]>(smem + 20480);   // [2][4][17][16]
    int lane = threadIdx.x & 63;
    int w = waveid();                  // 0..7
    int j = lane & 15, g = lane >> 4;
    int b = blockIdx.y;
    int n0 = blockIdx.x * 32;

    const unsigned short* qbb  = qb  + (size_t)b * NN * 32;
    const unsigned short* kbb  = kb  + (size_t)b * NN * 32;
    const unsigned short* vtbb = vtb + (size_t)b * DD * NN;
    short8_t qf0 = *reinterpret_cast<const short8_t*>(qbb + (n0 + j) * 32 + 8 * g);
    short8_t qf1 = *reinterpret_cast<const short8_t*>(qbb + (n0 + 16 + j) * 32 + 8 * g);

    f32x4 acc0 = {0.f, 0.f, 0.f, 0.f};
    f32x4 acc1 = {0.f, 0.f, 0.f, 0.f};
    unsigned int* bufA0 = plds[w][0];
    unsigned int* bufA1 = plds[w][1];
    unsigned int* bufB0 = plds[w][2];
    unsigned int* bufB1 = plds[w][3];
    for (int MC = w; MC < 128; MC += 16) {
        xr_body((MC)     * 32, bufA0, bufA1, kbb, vtbb, qf0, qf1, j, g, acc0, acc1);
        xr_body((MC + 8) * 32, bufB0, bufB1, kbb, vtbb, qf0, qf1, j, g, acc0, acc1);
    }
    __syncthreads();                    // all waves done with plds before xls aliases it
#pragma unroll
    for (int r = 0; r < 4; ++r) {
        xls[w][0][lane][r] = acc0[r];
        xls[w][1][lane][r] = acc1[r];
    }
    __syncthreads();
    if (w < 2) {                         // wave w owns n-subtile nt = w
        int nt = w;
        float tot[4];
#pragma unroll
        for (int r = 0; r < 4; ++r) {
            float s = 0.f;
#pragma unroll
            for (int ww = 0; ww < 8; ++ww) s += xls[ww][nt][lane][r];
            tot[r] = s;
        }
        size_t row = (size_t)b * NN + n0 + nt * 16 + j;
        const float4 q4 = *reinterpret_cast<const float4*>(q + row * DD + 4 * g);
        float d0 = q4.x - tot[0], d1 = q4.y - tot[1], d2 = q4.z - tot[2], d3 = q4.w - tot[3];
#pragma unroll
        for (int o = 0; o < DD; ++o) {
            const float4 wt = *reinterpret_cast<const float4*>(w_t + o * DD + 4 * g);
            pt[nt][g][o][j] = wt.x * d0 + wt.y * d1 + wt.z * d2 + wt.w * d3;
        }
        __builtin_amdgcn_s_waitcnt(0);   // lgkmcnt(0): same-wave LDS ordering
        const float4 bt4 = *reinterpret_cast<const float4*>(b_t + 4 * g);
        float tq[4];
#pragma unroll
        for (int i = 0; i < 4; ++i) {
            int o = 4 * g + i;
            tq[i] = pt[nt][0][o][j] + pt[nt][1][o][j] + pt[nt][2][o][j] + pt[nt][3][o][j];
        }
        tq[0] += bt4.x; tq[1] += bt4.y; tq[2] += bt4.z; tq[3] += bt4.w;
        float4 tout = {tq[0], tq[1], tq[2], tq[3]};
        *reinterpret_cast<float4*>(t + row * DD + 4 * g) = tout;
        float s  = tq[0] + tq[1] + tq[2] + tq[3];
        float sq = tq[0]*tq[0] + tq[1]*tq[1] + tq[2]*tq[2] + tq[3]*tq[3];
#pragma unroll
        for (int dlt = 1; dlt < 16; dlt <<= 1) {
            s  += __shfl_xor(s, dlt);
            sq += __shfl_xor(sq, dlt);
        }
        if (j == 0) {
            atomicAdd(&gnacc[(b * GG + g) * 2 + 0], s);
            atomicAdd(&gnacc[(b * GG + g) * 2 + 1], sq);
        }
    }
}

// K5: out = q + relu(gn(t)), LDS-transposed stores. grid NB*NN/64 = 256 blocks.
__global__ __launch_bounds__(256) void k_out(
    const float* __restrict__ q, const float* __restrict__ t,
    const float* __restrict__ gnacc, const float* __restrict__ gamma,
    const float* __restrict__ beta, float* __restrict__ out)
{
    __shared__ float tl[64][17], ql[64][17];
    int tid = threadIdx.x;
    int g0 = blockIdx.x * 64;          // row base (b*NN + n)
    int b = g0 >> 12;

    {
        float4 tv = *reinterpret_cast<const float4*>(t + (size_t)g0 * DD + tid * 4);
        float4 qv = *reinterpret_cast<const float4*>(q + (size_t)g0 * DD + tid * 4);
        int r = (tid * 4) >> 4, c = (tid * 4) & 15;
        tl[r][c] = tv.x; tl[r][c + 1] = tv.y; tl[r][c + 2] = tv.z; tl[r][c + 3] = tv.w;
        ql[r][c] = qv.x; ql[r][c + 1] = qv.y; ql[r][c + 2] = qv.z; ql[r][c + 3] = qv.w;
    }
    __syncthreads();

    int o = tid >> 4, n16 = tid & 15;
    int g = o >> 2;
    const float cnt = 1.0f / (4.0f * NN);
    float ms = gnacc[(b * GG + g) * 2 + 0];
    float sqs = gnacc[(b * GG + g) * 2 + 1];
    float mean = ms * cnt;
    float var = sqs * cnt - mean * mean;
    float rsig = rsqrtf(var + EPSGN);
    float ga = gamma[o], be = beta[o];

    int r0 = n16 * 4;
    float4 res;
    res.x = ql[r0    ][o] + fmaxf((tl[r0    ][o] - mean) * rsig * ga + be, 0.f);
    res.y = ql[r0 + 1][o] + fmaxf((tl[r0 + 1][o] - mean) * rsig * ga + be, 0.f);
    res.z = ql[r0 + 2][o] + fmaxf((tl[r0 + 2][o] - mean) * rsig * ga + be, 0.f);
    res.w = ql[r0 + 3][o] + fmaxf((tl[r0 + 3][o] - mean) * rsig * ga + be, 0.f);
    *reinterpret_cast<float4*>(out + ((size_t)(b * DD + o)) * NN + (g0 & (NN - 1)) + r0) = res;
}

extern "C" void kernel_launch(void* const* d_in, const int* in_sizes, int n_in,
                              void* d_out, int out_size, void* d_ws, size_t ws_size,
                              hipStream_t stream)
{
    const float* x_q      = (const float*)d_in[0];
    const float* x_kv     = (const float*)d_in[1];
    const float* xyz_q    = (const float*)d_in[2];
    const float* xyz_kv   = (const float*)d_in[3];
    const float* w_qk     = (const float*)d_in[4];
    const float* w_v      = (const float*)d_in[5];
    const float* b_v      = (const float*)d_in[6];
    const float* w_t      = (const float*)d_in[7];
    const float* b_t      = (const float*)d_in[8];
    const float* gamma    = (const float*)d_in[9];
    const float* beta     = (const float*)d_in[10];
    const float* w_pos_q  = (const float*)d_in[11];
    const float* w_pos_kv = (const float*)d_in[12];

    float* ws = (float*)d_ws;
    float* q       = ws + OFF_Q;
    float* t       = ws + OFF_T;
    float* gnacc   = ws + OFF_GN;
    unsigned short* qb  = (unsigned short*)(ws + OFF_QB);
    unsigned short* kb  = (unsigned short*)(ws + OFF_KB);
    unsigned short* vtb = (unsigned short*)(ws + OFF_VTB);
    float* out     = (float*)d_out;

    k_qkv<<<dim3(NB * NN / 64), 512, 0, stream>>>(
        x_q, x_kv, xyz_q, xyz_kv, w_qk, w_v, b_v, w_pos_q, w_pos_kv,
        q, qb, kb, vtb, gnacc);

    k_rows<<<dim3(NN / 32, NB), 512, 0, stream>>>(qb, kb);
    k_cols<<<dim3(NN / 32, NB), 512, 0, stream>>>(qb, kb);
    k_xr<<<dim3(NN / 32, NB), 512, 0, stream>>>(qb, kb, vtb, q, w_t, b_t, t, gnacc);
    k_out<<<dim3(NB * NN / 64), 256, 0, stream>>>(q, t, gnacc, gamma, beta, out);
}